// Round 15
// baseline (265.928 us; speedup 1.0000x reference)
//
#include <hip/hip_runtime.h>
#include <hip/hip_bf16.h>
#include <cstdint>
#include <cstddef>

#define NH   16
#define DH   64
#define SQ   2048
#define NB   2
#define EM   1024
#define NREL 257
#define QSTR 258          // qrel row stride (elements)
#define SCL  0.18033688f  // 0.125 * log2(e)
#define NR   ((size_t)NB * NH * SQ)   // 65536 rows
#define NQE  (NB * SQ * EM)           // 4194304
#define NWE  (EM * EM)                // 1048576

typedef unsigned short ushort_t;
using bf16x8 = __attribute__((ext_vector_type(8))) __bf16;
using bf16x4 = __attribute__((ext_vector_type(4))) __bf16;
using f32x4  = __attribute__((ext_vector_type(4))) float;
#define MFMA16(a, b, c) __builtin_amdgcn_mfma_f32_16x16x32_bf16(a, b, c, 0, 0, 0)

__device__ __forceinline__ ushort_t f2bf(float f) {
    union { __bf16 h; ushort_t u; } x; x.h = (__bf16)f; return x.u;
}
__device__ __forceinline__ float bf2f(ushort_t u) {
    union { unsigned u; float f; } x; x.u = ((unsigned)u) << 16;
    return x.f;
}
__device__ __forceinline__ uint2 pack4(float a, float b, float c, float d) {
    union { bf16x4 v; uint2 u; } x;
    x.v = (bf16x4){ (__bf16)a, (__bf16)b, (__bf16)c, (__bf16)d };
    return x.u;
}
// kappa permutation within a 64-block: k = 16n + c16  ->  kap = 4*c16 + n
__device__ __forceinline__ int kperm(int x) {
    return (x & ~63) | ((x & 15) << 2) | ((x >> 4) & 3);
}
// LDS swizzle for 128B-row tiles: XOR 16B-slot by row&7 (kills the 8-way
// staging-write conflict of the linear layout; reads use the same XOR)
__device__ __forceinline__ int lswz(int row, int byteoff) {
    return row * 128 + (byteoff ^ ((row & 7) << 4));
}
// HBM -> LDS direct, 16B per lane (lane l lands at ldsbase + l*16)
__device__ __forceinline__ void gl_lds16(const void* g, void* l) {
    __builtin_amdgcn_global_load_lds(
        (const __attribute__((address_space(1))) unsigned int*)g,
        (__attribute__((address_space(3))) unsigned int*)l, 16, 0, 0);
}

// ---------------------------------------------------------------------------
// single-launch f32->bf16 convert for all 7 arrays (y selects slice)
// ---------------------------------------------------------------------------
__global__ __launch_bounds__(256)
void cvt7(const float* __restrict__ q, const float* __restrict__ k,
          const float* __restrict__ v, const float* __restrict__ Wq,
          const float* __restrict__ Wk, const float* __restrict__ Wv,
          const float* __restrict__ Wo,
          ushort_t* __restrict__ oq, ushort_t* __restrict__ ok,
          ushort_t* __restrict__ ov, ushort_t* __restrict__ oWq,
          ushort_t* __restrict__ oWk, ushort_t* __restrict__ oWv,
          ushort_t* __restrict__ oWo)
{
    const int y = blockIdx.y;
    const float* in; ushort_t* out; int n;
    switch (y) {
        case 0: in = q;  out = oq;  n = NQE; break;
        case 1: in = k;  out = ok;  n = NQE; break;
        case 2: in = v;  out = ov;  n = NQE; break;
        case 3: in = Wq; out = oWq; n = NWE; break;
        case 4: in = Wk; out = oWk; n = NWE; break;
        case 5: in = Wv; out = oWv; n = NWE; break;
        default: in = Wo; out = oWo; n = NWE; break;
    }
    int i = (blockIdx.x * 256 + threadIdx.x) * 8;
    if (i < n) {
        float4 v0 = *reinterpret_cast<const float4*>(in + i);
        float4 v1 = *reinterpret_cast<const float4*>(in + i + 4);
        uint2 lo = pack4(v0.x, v0.y, v0.z, v0.w);
        uint2 hi = pack4(v1.x, v1.y, v1.z, v1.w);
        *reinterpret_cast<uint4*>(out + i) = make_uint4(lo.x, lo.y, hi.x, hi.y);
    }
}

// rvT[d][kperm(c)] = rv[c+1][d] bf16 (c in [0,256)); rkb zero-padded to 272 rows
__global__ __launch_bounds__(256)
void prep_tables(const float* __restrict__ rv, const float* __restrict__ rk,
                 ushort_t* __restrict__ rvT, ushort_t* __restrict__ rkb)
{
    int idx = blockIdx.x * 256 + threadIdx.x;
    if (idx < 64 * 256) {
        int d = idx >> 8, c = idx & 255;
        rvT[d * 256 + kperm(c)] = f2bf(rv[(size_t)(c + 1) * DH + d]);
    }
    idx -= 64 * 256;
    if (idx >= 0 && idx < 272 * 64) {
        int j = idx >> 6, d2 = idx & 63;
        rkb[idx] = (j < NREL) ? f2bf(rk[(size_t)j * DH + d2]) : (ushort_t)0;
    }
}

// ---------------------------------------------------------------------------
// Merged Q/K/V projection GEMM, one launch (z selects slice; z==2 -> V mode).
// 128x64 tile, BK=32, 4 waves, gl_lds width-16 staging.
// ---------------------------------------------------------------------------
__global__ __launch_bounds__(256)
void gemm_qkv(const ushort_t* __restrict__ qbf, const ushort_t* __restrict__ kbf,
              const ushort_t* __restrict__ vbf, const ushort_t* __restrict__ Wqb,
              const ushort_t* __restrict__ Wkb, const ushort_t* __restrict__ Wvb,
              const float* __restrict__ bq, const float* __restrict__ bk,
              const float* __restrict__ bv, ushort_t* __restrict__ qhb,
              ushort_t* __restrict__ khb, ushort_t* __restrict__ vtb)
{
    __shared__ ushort_t As[128 * 32];
    __shared__ ushort_t Bs[64 * 32];
    const int z = blockIdx.z;
    const ushort_t* A = z == 0 ? qbf : (z == 1 ? kbf : vbf);
    const ushort_t* W = z == 0 ? Wqb : (z == 1 ? Wkb : Wvb);
    const float* bias = z == 0 ? bq : (z == 1 ? bk : bv);
    ushort_t* dst     = z == 0 ? qhb : (z == 1 ? khb : vtb);
    const bool vmode  = (z == 2);
    const int K = EM;

    const int t = threadIdx.x, lane = t & 63;
    const int wv = t >> 6, wr = wv >> 1, wc = wv & 1;
    const int g = lane >> 4, c16 = lane & 15;
    const int rowi = lane >> 2, chi = lane & 3;   // staging: 16 rows x 4 chunks

    const int nwg = gridDim.x * gridDim.y;        // 512 per slice
    int flat = blockIdx.y * gridDim.x + blockIdx.x;
    int rm = (flat & 7) * (nwg >> 3) + (flat >> 3);
    const int n0 = (rm % gridDim.x) * 64;
    const int m0 = (rm / gridDim.x) * 128;

    f32x4 acc[4][2];
#pragma unroll
    for (int i = 0; i < 4; ++i)
#pragma unroll
        for (int j = 0; j < 2; ++j) acc[i][j] = (f32x4){0.f, 0.f, 0.f, 0.f};

    for (int k0 = 0; k0 < K; k0 += 32) {
        __syncthreads();
#pragma unroll
        for (int j = 0; j < 2; ++j) {
            const int rbase = wv * 32 + j * 16;   // wave-uniform A rows
            gl_lds16(A + (size_t)(m0 + rbase + rowi) * K + k0 + chi * 8,
                     As + rbase * 32);
        }
        {
            const int rbase = wv * 16;            // wave-uniform B rows
            gl_lds16(W + (size_t)(n0 + rbase + rowi) * K + k0 + chi * 8,
                     Bs + rbase * 32);
        }
        __syncthreads();

        bf16x8 af[4], bfr[2];
#pragma unroll
        for (int i = 0; i < 4; ++i)
            af[i] = *reinterpret_cast<const bf16x8*>(As + (wr * 64 + i * 16 + c16) * 32 + g * 8);
#pragma unroll
        for (int j = 0; j < 2; ++j)
            bfr[j] = *reinterpret_cast<const bf16x8*>(Bs + (wc * 32 + j * 16 + c16) * 32 + g * 8);
#pragma unroll
        for (int i = 0; i < 4; ++i)
#pragma unroll
            for (int j = 0; j < 2; ++j)
                acc[i][j] = MFMA16(af[i], bfr[j], acc[i][j]);
    }

#pragma unroll
    for (int j = 0; j < 2; ++j) {
        const int n = n0 + wc * 32 + j * 16 + c16;
        const float bn = bias[n];
#pragma unroll
        for (int i = 0; i < 4; ++i) {
#pragma unroll
            for (int r = 0; r < 4; ++r) {
                const int m = m0 + wr * 64 + i * 16 + 4 * g + r;
                const float vv = acc[i][j][r] + bn;
                const int b = m >> 11, s = m & (SQ - 1);
                const int h = n >> 6, dd = n & 63;
                if (!vmode) {
                    dst[(((size_t)b * NH + h) * SQ + s) * DH + dd] = f2bf(vv);
                } else {
                    const int sp = kperm(s);
                    dst[(((size_t)b * NH + h) * DH + dd) * SQ + sp] = f2bf(vv);
                }
            }
        }
    }
}

// ---------------------------------------------------------------------------
// Final output GEMM: f32 dst = A @ W^T + bias; 128x64 tile.
// ---------------------------------------------------------------------------
__global__ __launch_bounds__(256)
void gemm_out(const ushort_t* __restrict__ A, const ushort_t* __restrict__ W,
              const float* __restrict__ bias, float* __restrict__ dst,
              int M, int N, int K)
{
    __shared__ ushort_t As[128 * 32];
    __shared__ ushort_t Bs[64 * 32];
    const int t = threadIdx.x, lane = t & 63;
    const int wv = t >> 6, wr = wv >> 1, wc = wv & 1;
    const int g = lane >> 4, c16 = lane & 15;
    const int rowi = lane >> 2, chi = lane & 3;

    const int nwg = gridDim.x * gridDim.y;
    int flat = blockIdx.y * gridDim.x + blockIdx.x;
    int rm = (flat & 7) * (nwg >> 3) + (flat >> 3);
    const int n0 = (rm % gridDim.x) * 64;
    const int m0 = (rm / gridDim.x) * 128;

    f32x4 acc[4][2];
#pragma unroll
    for (int i = 0; i < 4; ++i)
#pragma unroll
        for (int j = 0; j < 2; ++j) acc[i][j] = (f32x4){0.f, 0.f, 0.f, 0.f};

    for (int k0 = 0; k0 < K; k0 += 32) {
        __syncthreads();
#pragma unroll
        for (int j = 0; j < 2; ++j) {
            const int rbase = wv * 32 + j * 16;
            gl_lds16(A + (size_t)(m0 + rbase + rowi) * K + k0 + chi * 8,
                     As + rbase * 32);
        }
        {
            const int rbase = wv * 16;
            gl_lds16(W + (size_t)(n0 + rbase + rowi) * K + k0 + chi * 8,
                     Bs + rbase * 32);
        }
        __syncthreads();

        bf16x8 af[4], bfr[2];
#pragma unroll
        for (int i = 0; i < 4; ++i)
            af[i] = *reinterpret_cast<const bf16x8*>(As + (wr * 64 + i * 16 + c16) * 32 + g * 8);
#pragma unroll
        for (int j = 0; j < 2; ++j)
            bfr[j] = *reinterpret_cast<const bf16x8*>(Bs + (wc * 32 + j * 16 + c16) * 32 + g * 8);
#pragma unroll
        for (int i = 0; i < 4; ++i)
#pragma unroll
            for (int j = 0; j < 2; ++j)
                acc[i][j] = MFMA16(af[i], bfr[j], acc[i][j]);
    }

#pragma unroll
    for (int j = 0; j < 2; ++j) {
        const int n = n0 + wc * 32 + j * 16 + c16;
        const float bn = bias[n];
#pragma unroll
        for (int i = 0; i < 4; ++i)
#pragma unroll
            for (int r = 0; r < 4; ++r) {
                const int m = m0 + wr * 64 + i * 16 + 4 * g + r;
                dst[(size_t)m * N + n] = acc[i][j][r] + bn;
            }
    }
}

// ---------------------------------------------------------------------------
// qrel[r][j] = dot(qh[r], rk[j]) * SCL, bf16 out, stride QSTR.
// ---------------------------------------------------------------------------
__global__ __launch_bounds__(256)
void qrel_mfma(const ushort_t* __restrict__ qh, const ushort_t* __restrict__ rkb,
               ushort_t* __restrict__ qrel)
{
    const int t = threadIdx.x, lane = t & 63, w = t >> 6;
    const int g = lane >> 4, c16 = lane & 15;
    const size_t r0 = (size_t)blockIdx.x * 64 + w * 16;

    bf16x8 af[2];
#pragma unroll
    for (int ks = 0; ks < 2; ++ks)
        af[ks] = *reinterpret_cast<const bf16x8*>(qh + (r0 + c16) * DH + ks * 32 + g * 8);

    f32x4 acc[17];
#pragma unroll
    for (int n = 0; n < 17; ++n) acc[n] = (f32x4){0.f, 0.f, 0.f, 0.f};
#pragma unroll
    for (int n = 0; n < 17; ++n)
#pragma unroll
        for (int ks = 0; ks < 2; ++ks) {
            bf16x8 bf = *reinterpret_cast<const bf16x8*>(
                rkb + (size_t)(16 * n + c16) * DH + ks * 32 + g * 8);
            acc[n] = MFMA16(af[ks], bf, acc[n]);
        }
#pragma unroll
    for (int n = 0; n < 17; ++n) {
        const int j = 16 * n + c16;
        if (j < NREL) {
#pragma unroll
            for (int r = 0; r < 4; ++r)
                qrel[(r0 + 4 * g + r) * QSTR + j] = f2bf(acc[n][r] * SCL);
        }
    }
}

// ---------------------------------------------------------------------------
// Flash attention: round-14 structure, LDS layout changed to 128B-row XOR
// swizzle (writes AND reads) to kill the 8-way staging-write bank conflict.
// QBLK=64, single-tile staging with reg prefetch, 2 barriers/tile.
// w1 = P@V (kappa-space), lac/b0/b256; band P tiles (5/q-block) -> Ptile.
// ---------------------------------------------------------------------------
__global__ __launch_bounds__(256, 4)
void attn_flash(const ushort_t* __restrict__ qh, const ushort_t* __restrict__ kh,
                const ushort_t* __restrict__ vt, const ushort_t* __restrict__ qrel,
                ushort_t* __restrict__ Ptile, float* __restrict__ w1g,
                float* __restrict__ lacg, float* __restrict__ b0g,
                float* __restrict__ b256g)
{
    __shared__ ushort_t Ks[64 * 64];
    __shared__ ushort_t Vs[64 * 64];
    __shared__ ushort_t PQs[64 * 64];   // Q at start, then P (kappa cols)
    char* Ksb = (char*)Ks; char* Vsb = (char*)Vs; char* PQb = (char*)PQs;

    const int t = threadIdx.x, lane = t & 63, w = t >> 6;
    const int g = lane >> 4, c16 = lane & 15;
    const int nwg = gridDim.x * gridDim.y;
    int flat = blockIdx.y * gridDim.x + blockIdx.x;
    int rmid = (flat & 7) * (nwg >> 3) + (flat >> 3);
    const int q0 = (rmid & 31) * 64;
    const int bh = rmid >> 5;
    const size_t Gbase = ((size_t)bh * 32 + (q0 >> 6)) * 5;

    // stage Q -> LDS (swizzled) -> register fragments
#pragma unroll
    for (int l = 0; l < 2; ++l) {
        const int fid = t + 256 * l;
        const int row = fid >> 3, ch = fid & 7;
        uint4 v = *reinterpret_cast<const uint4*>(
            qh + ((size_t)bh * SQ + q0 + row) * DH + ch * 8);
        *reinterpret_cast<uint4*>(PQb + lswz(row, ch * 16)) = v;
    }
    __syncthreads();
    bf16x8 qf[2];
#pragma unroll
    for (int ks = 0; ks < 2; ++ks)
        qf[ks] = *reinterpret_cast<const bf16x8*>(
            PQb + lswz(w * 16 + c16, ks * 64 + g * 16));

    const ushort_t* qrb = qrel + ((size_t)bh * SQ + q0) * QSTR;
    float q0add[4], q256add[4];
#pragma unroll
    for (int i = 0; i < 4; ++i) {
        const int r = w * 16 + 4 * g + i;
        q0add[i]   = bf2f(qrb[(size_t)r * QSTR + 0]);
        q256add[i] = bf2f(qrb[(size_t)r * QSTR + 256]);
    }

    f32x4 w1[4];
#pragma unroll
    for (int n = 0; n < 4; ++n) w1[n] = (f32x4){0.f, 0.f, 0.f, 0.f};
    float lac[4] = {0.f,0.f,0.f,0.f}, b0[4] = {0.f,0.f,0.f,0.f}, b256[4] = {0.f,0.f,0.f,0.f};

    // pipelined staging registers
    const int row_l = t >> 3, ch_l = t & 7;
    const int row_h = row_l + 32;
    uint4 kr0, kr1, vr0, vr1;
    {
        kr0 = *reinterpret_cast<const uint4*>(kh + ((size_t)bh * SQ + row_l) * DH + ch_l * 8);
        kr1 = *reinterpret_cast<const uint4*>(kh + ((size_t)bh * SQ + row_h) * DH + ch_l * 8);
        vr0 = *reinterpret_cast<const uint4*>(vt + ((size_t)bh * DH + row_l) * SQ + ch_l * 8);
        vr1 = *reinterpret_cast<const uint4*>(vt + ((size_t)bh * DH + row_h) * SQ + ch_l * 8);
    }

    for (int k0 = 0; k0 < SQ; k0 += 64) {
        __syncthreads();   // prev tile's MFMA LDS reads done (also covers qf loads)
        *reinterpret_cast<uint4*>(Ksb + lswz(row_l, ch_l * 16)) = kr0;
        *reinterpret_cast<uint4*>(Ksb + lswz(row_h, ch_l * 16)) = kr1;
        *reinterpret_cast<uint4*>(Vsb + lswz(row_l, ch_l * 16)) = vr0;
        *reinterpret_cast<uint4*>(Vsb + lswz(row_h, ch_l * 16)) = vr1;
        __syncthreads();
        if (k0 + 64 < SQ) {   // prefetch next tile; latency hidden by compute
            kr0 = *reinterpret_cast<const uint4*>(kh + ((size_t)bh * SQ + k0 + 64 + row_l) * DH + ch_l * 8);
            kr1 = *reinterpret_cast<const uint4*>(kh + ((size_t)bh * SQ + k0 + 64 + row_h) * DH + ch_l * 8);
            vr0 = *reinterpret_cast<const uint4*>(vt + ((size_t)bh * DH + row_l) * SQ + k0 + 64 + ch_l * 8);
            vr1 = *reinterpret_cast<const uint4*>(vt + ((size_t)bh * DH + row_h) * SQ + k0 + 64 + ch_l * 8);
        }

        f32x4 s[4];
#pragma unroll
        for (int n = 0; n < 4; ++n) s[n] = (f32x4){0.f, 0.f, 0.f, 0.f};
        {
            bf16x8 kf[4][2];
#pragma unroll
            for (int n = 0; n < 4; ++n)
#pragma unroll
                for (int ks = 0; ks < 2; ++ks)
                    kf[n][ks] = *reinterpret_cast<const bf16x8*>(
                        Ksb + lswz(16 * n + c16, ks * 64 + g * 16));
            __builtin_amdgcn_s_setprio(1);
#pragma unroll
            for (int ks = 0; ks < 2; ++ks)
#pragma unroll
                for (int n = 0; n < 4; ++n)
                    s[n] = MFMA16(qf[ks], kf[n][ks], s[n]);
            __builtin_amdgcn_s_setprio(0);
        }

        const int rel0 = k0 - q0;
        float rsum[4] = {0.f, 0.f, 0.f, 0.f};
        if (rel0 <= -192 || rel0 >= 192) {                 // far: uniform bias
            const bool lo = rel0 < 0;
#pragma unroll
            for (int i = 0; i < 4; ++i) {
                const float add = lo ? q0add[i] : q256add[i];
#pragma unroll
                for (int n = 0; n < 4; ++n) {
                    const float p = exp2f(fmaf(s[n][i], SCL, add));
                    s[n][i] = p; rsum[i] += p;
                }
                if (lo) b0[i] += rsum[i]; else b256[i] += rsum[i];
                const int qloc = w * 16 + 4 * g + i;
                *reinterpret_cast<uint2*>(PQb + lswz(qloc, c16 * 8)) =
                    pack4(s[0][i], s[1][i], s[2][i], s[3][i]);
            }
        } else if (rel0 == -128 || rel0 == 128) {          // mixed band edge
            const int tix = (rel0 + 128) >> 6;
#pragma unroll
            for (int i = 0; i < 4; ++i) {
                const int qloc = w * 16 + 4 * g + i;
                const ushort_t* qrow = qrb + (size_t)qloc * QSTR;
                float z[4];
#pragma unroll
                for (int n = 0; n < 4; ++n) {
                    const int rel = rel0 + 16 * n + c16 - qloc;
                    const int idx = rel < -128 ? 0 : (rel > 128 ? 256 : rel + 128);
                    const float p = exp2f(fmaf(s[n][i], SCL, bf2f(qrow[idx])));
                    s[n][i] = p; rsum[i] += p;
                    const bool inb = (rel >= -127) & (rel <= 127);
                    z[n] = inb ? p : 0.f;
                    if (rel <= -128)      b0[i] += p;
                    else if (rel >= 128)  b256[i] += p;
                }
                *reinterpret_cast<uint2*>(PQb + lswz(qloc, c16 * 8)) =
                    pack4(s[0][i], s[1][i], s[2][i], s[3][i]);
                *reinterpret_cast<uint2*>(
                    Ptile + ((Gbase + tix) * 64 + qloc) * 64 + 4 * c16) =
                    pack4(z[0], z[1], z[2], z[3]);
            }
        } else {                                           // pure band: no clamp
            const int tix = (rel0 + 128) >> 6;
#pragma unroll
            for (int i = 0; i < 4; ++i) {
                const int qloc = w * 16 + 4 * g + i;
                const ushort_t* qrow = qrb + (size_t)qloc * QSTR;
#pragma unroll
                for (int n = 0; n < 4; ++n) {
                    const int rel = rel0 + 16 * n + c16 - qloc;
                    const float p = exp2f(fmaf(s[n][i], SCL, bf2f(qrow[rel + 128])));
                    s[n][i] = p; rsum[i] += p;
                }
                const uint2 pk = pack4(s[0][i], s[1][i], s[2][i], s[3][i]);
                *reinterpret_cast<uint2*>(PQb + lswz(qloc, c16 * 8)) = pk;
                *reinterpret_cast<uint2*>(
                    Ptile + ((Gbase + tix) * 64 + qloc) * 64 + 4 * c16) = pk;
            }
        }
#pragma unroll
        for (int i = 0; i < 4; ++i) lac[i] += rsum[i];

        // w1 += P @ V
        {
            bf16x8 vf[4][2];
#pragma unroll
            for (int n = 0; n < 4; ++n)
#pragma unroll
                for (int ks = 0; ks < 2; ++ks)
                    vf[n][ks] = *reinterpret_cast<const bf16x8*>(
                        Vsb + lswz(16 * n + c16, ks * 64 + g * 16));
            bf16x8 pf[2];
#pragma unroll
            for (int ks = 0; ks < 2; ++ks)
                pf[ks] = *reinterpret_cast<const bf16x8*>(
                    PQb + lswz(w * 16 + c16, ks * 64 + g * 16));
            __builtin_amdgcn_s_setprio(1);
#pragma unroll
            for (int ks = 0; ks < 2; ++ks)
#pragma unroll
                for (int n = 0; n < 4; ++n)
                    w1[n] = MFMA16(pf[ks], vf[n][ks], w1[n]);
            __builtin_amdgcn_s_setprio(0);
        }
    }

#pragma unroll
    for (int m = 1; m < 16; m <<= 1)
#pragma unroll
        for (int i = 0; i < 4; ++i) {
            lac[i]  += __shfl_xor(lac[i],  m, 64);
            b0[i]   += __shfl_xor(b0[i],   m, 64);
            b256[i] += __shfl_xor(b256[i], m, 64);
        }
    if (c16 == 0) {
#pragma unroll
        for (int i = 0; i < 4; ++i) {
            const size_t row = (size_t)bh * SQ + q0 + w * 16 + 4 * g + i;
            lacg[row] = lac[i]; b0g[row] = b0[i]; b256g[row] = b256[i];
        }
    }
#pragma unroll
    for (int n = 0; n < 4; ++n)
#pragma unroll
        for (int i = 0; i < 4; ++i) {
            const size_t row = (size_t)bh * SQ + q0 + w * 16 + 4 * g + i;
            w1g[row * DH + 16 * n + c16] = w1[n][i];
        }
}

// ---------------------------------------------------------------------------
// Band GEMM + combine: scatter 5 P tiles into shifted LDS layout
// Pband[q][kperm(rel+127)] (bucket 255 = b256 mass), w2 = Pband @ rvT^T,
// out = (w1 + w2 + b0*rv[0]) / lac -> wbuf [B,S,H,D] bf16.
// ---------------------------------------------------------------------------
__global__ __launch_bounds__(256)
void band_gemm(const ushort_t* __restrict__ Ptile, const ushort_t* __restrict__ rvT,
               const float* __restrict__ rv_f32, const float* __restrict__ w1g,
               const float* __restrict__ lacg, const float* __restrict__ b0g,
               const float* __restrict__ b256g, ushort_t* __restrict__ wout)
{
    __shared__ ushort_t Pband[64 * 264];
    const int t = threadIdx.x, lane = t & 63, w = t >> 6;
    const int g = lane >> 4, c16 = lane & 15;
    const int G = blockIdx.x;             // q-block id (= bh*32 + qb)
    const size_t r0 = (size_t)G * 64;
    const int q0 = (G & 31) * 64;

    for (int i = t; i < 64 * 264 / 2; i += 256)
        reinterpret_cast<unsigned*>(Pband)[i] = 0u;
    __syncthreads();

    // scatter tiles (coalesced reads, LDS b16 scatter)
    for (int u = t; u < 5 * 64 * 16; u += 256) {
        const int tix = u >> 10;
        const int kt0 = q0 + (tix - 2) * 64;
        if (kt0 < 0 || kt0 >= SQ) continue;
        const int qloc = (u >> 4) & 63;
        const int c = u & 15;
        uint2 pv = *reinterpret_cast<const uint2*>(
            Ptile + (((size_t)G * 5 + tix) * 64 + qloc) * 64 + 4 * c);
        const ushort_t* pe = reinterpret_cast<const ushort_t*>(&pv);
        const int relbase = (tix - 2) * 64 - qloc + 127;
#pragma unroll
        for (int n = 0; n < 4; ++n) {
            const int x = relbase + 16 * n + c;
            if (x >= 0 && x <= 254)
                Pband[qloc * 264 + ((x & ~63) | ((x & 15) << 2) | ((x >> 4) & 3))] = pe[n];
        }
    }
    if (t < 64) Pband[t * 264 + 255] = f2bf(b256g[r0 + t]);
    __syncthreads();

    f32x4 acc[4];
#pragma unroll
    for (int n = 0; n < 4; ++n) acc[n] = (f32x4){0.f, 0.f, 0.f, 0.f};
#pragma unroll
    for (int ks = 0; ks < 8; ++ks) {
        bf16x8 pm = *reinterpret_cast<const bf16x8*>(
            Pband + (w * 16 + c16) * 264 + ks * 32 + g * 8);
#pragma unroll
        for (int n = 0; n < 4; ++n) {
            bf16x8 rf = *reinterpret_cast<const bf16x8*>(
                rvT + (size_t)(16 * n + c16) * 256 + ks * 32 + g * 8);
            acc[n] = MFMA16(pm, rf, acc[n]);
        }
    }

#pragma unroll
    for (int i = 0; i < 4; ++i) {
        const size_t row = r0 + w * 16 + 4 * g + i;
        const float inv = 1.0f / lacg[row];
        const float vb0 = b0g[row];
        const int b = (int)(row >> 15), h = (int)((row >> 11) & 15), s = (int)(row & 2047);
#pragma unroll
        for (int n = 0; n < 4; ++n) {
            const int col = 16 * n + c16;
            const float val = (w1g[row * DH + col] + acc[n][i] + vb0 * rv_f32[col]) * inv;
            wout[(((size_t)b * SQ + s) * NH + h) * DH + col] = f2bf(val);
        }
    }
}

// ---------------------------------------------------------------------------
extern "C" void kernel_launch(void* const* d_in, const int* in_sizes, int n_in,
                              void* d_out, int out_size, void* d_ws, size_t ws_size,
                              hipStream_t stream)
{
    const float* q  = (const float*)d_in[0];
    const float* k  = (const float*)d_in[1];
    const float* v  = (const float*)d_in[2];
    const float* Wq = (const float*)d_in[3];
    const float* bq = (const float*)d_in[4];
    const float* Wk = (const float*)d_in[5];
    const float* bk = (const float*)d_in[6];
    const float* Wv = (const float*)d_in[7];
    const float* bv = (const float*)d_in[8];
    const float* Wo = (const float*)d_in[9];
    const float* bo = (const float*)d_in[10];
    const float* rk = (const float*)d_in[11];
    const float* rv = (const float*)d_in[12];

    char* ws = (char*)d_ws;
    auto alloc = [&](size_t bytes) { char* p = ws; ws += bytes; return p; };
    const size_t QB = (size_t)NB * SQ * EM * 2;       // 8 MB
    const size_t WB = (size_t)EM * EM * 2;            // 2 MB

    // Ptile aliases the early bf16 staging buffers (dead before flash runs).
    char* region0 = alloc(NR * 320 * 2);              // 41.9 MB
    ushort_t* Ptile = (ushort_t*)region0;             // [NR/64][5][64][64]
    ushort_t* qbf = (ushort_t*)region0;
    ushort_t* kbf = (ushort_t*)(region0 + QB);
    ushort_t* vbf = (ushort_t*)(region0 + 2 * QB);
    ushort_t* Wqb = (ushort_t*)(region0 + 3 * QB);
    ushort_t* Wkb = (ushort_t*)(region0 + 3 * QB + WB);
    ushort_t* Wvb = (ushort_t*)(region0 + 3 * QB + 2 * WB);   // ends at 30 MB < 41.9

    ushort_t* Wob  = (ushort_t*)alloc(WB);            // survives until final GEMM
    ushort_t* qhb  = (ushort_t*)alloc(QB);            // [B,H,S,D]
    ushort_t* khb  = (ushort_t*)alloc(QB);            // [B,H,S,D]
    ushort_t* vtb  = (ushort_t*)alloc(QB);            // [B,H,D,S'] kappa-permuted
    ushort_t* wbuf = (ushort_t*)alloc(QB);            // [B,S,H,D]
    ushort_t* rvT  = (ushort_t*)alloc(64 * 256 * 2);
    ushort_t* rkb  = (ushort_t*)alloc(272 * 64 * 2);
    ushort_t* qrel = (ushort_t*)alloc(NR * QSTR * 2);
    float*    w1g  = (float*)alloc(NR * DH * 4);
    float*    lacg = (float*)alloc(NR * 4);
    float*    b0g  = (float*)alloc(NR * 4);
    float*    b256g= (float*)alloc(NR * 4);

    cvt7<<<dim3(NQE / 2048, 7), 256, 0, stream>>>(
        q, k, v, Wq, Wk, Wv, Wo, qbf, kbf, vbf, Wqb, Wkb, Wvb, Wob);
    prep_tables<<<132, 256, 0, stream>>>(rv, rk, rvT, rkb);

    const int M = NB * SQ;
    gemm_qkv<<<dim3(EM / 64, M / 128, 3), 256, 0, stream>>>(
        qbf, kbf, vbf, Wqb, Wkb, Wvb, bq, bk, bv, qhb, khb, vtb);
    qrel_mfma<<<(int)(NR / 64), 256, 0, stream>>>(qhb, rkb, qrel);

    attn_flash<<<dim3(32, 32), 256, 0, stream>>>(qhb, khb, vtb, qrel,
                                                 Ptile, w1g, lacg, b0g, b256g);
    band_gemm<<<(int)(NR / 64), 256, 0, stream>>>(Ptile, rvT, rv, w1g, lacg,
                                                  b0g, b256g, wbuf);
    gemm_out<<<dim3(EM / 64, M / 128), 256, 0, stream>>>(
        wbuf, Wob, bo, (float*)d_out, M, EM, EM);
}

// Round 16
// 257.817 us; speedup vs baseline: 1.0315x; 1.0315x over previous
//
#include <hip/hip_runtime.h>
#include <hip/hip_bf16.h>
#include <cstdint>
#include <cstddef>

#define NH   16
#define DH   64
#define SQ   2048
#define NB   2
#define EM   1024
#define NREL 257
#define QSTR 258          // qrel row stride (elements)
#define SCL  0.18033688f  // 0.125 * log2(e)
#define NR   ((size_t)NB * NH * SQ)   // 65536 rows
#define NQE  (NB * SQ * EM)           // 4194304
#define NWE  (EM * EM)                // 1048576

typedef unsigned short ushort_t;
using bf16x8 = __attribute__((ext_vector_type(8))) __bf16;
using bf16x4 = __attribute__((ext_vector_type(4))) __bf16;
using f32x4  = __attribute__((ext_vector_type(4))) float;
#define MFMA16(a, b, c) __builtin_amdgcn_mfma_f32_16x16x32_bf16(a, b, c, 0, 0, 0)

__device__ __forceinline__ ushort_t f2bf(float f) {
    union { __bf16 h; ushort_t u; } x; x.h = (__bf16)f; return x.u;
}
__device__ __forceinline__ float bf2f(ushort_t u) {
    union { unsigned u; float f; } x; x.u = ((unsigned)u) << 16;
    return x.f;
}
__device__ __forceinline__ uint2 pack4(float a, float b, float c, float d) {
    union { bf16x4 v; uint2 u; } x;
    x.v = (bf16x4){ (__bf16)a, (__bf16)b, (__bf16)c, (__bf16)d };
    return x.u;
}
// kappa permutation within a 64-block: k = 16n + c16  ->  kap = 4*c16 + n
__device__ __forceinline__ int kperm(int x) {
    return (x & ~63) | ((x & 15) << 2) | ((x >> 4) & 3);
}
// HBM -> LDS direct, 16B per lane (lane l lands at ldsbase + l*16)
__device__ __forceinline__ void gl_lds16(const void* g, void* l) {
    __builtin_amdgcn_global_load_lds(
        (const __attribute__((address_space(1))) unsigned int*)g,
        (__attribute__((address_space(3))) unsigned int*)l, 16, 0, 0);
}

// ---------------------------------------------------------------------------
// single-launch f32->bf16 convert for all 7 arrays (y selects slice)
// ---------------------------------------------------------------------------
__global__ __launch_bounds__(256)
void cvt7(const float* __restrict__ q, const float* __restrict__ k,
          const float* __restrict__ v, const float* __restrict__ Wq,
          const float* __restrict__ Wk, const float* __restrict__ Wv,
          const float* __restrict__ Wo,
          ushort_t* __restrict__ oq, ushort_t* __restrict__ ok,
          ushort_t* __restrict__ ov, ushort_t* __restrict__ oWq,
          ushort_t* __restrict__ oWk, ushort_t* __restrict__ oWv,
          ushort_t* __restrict__ oWo)
{
    const int y = blockIdx.y;
    const float* in; ushort_t* out; int n;
    switch (y) {
        case 0: in = q;  out = oq;  n = NQE; break;
        case 1: in = k;  out = ok;  n = NQE; break;
        case 2: in = v;  out = ov;  n = NQE; break;
        case 3: in = Wq; out = oWq; n = NWE; break;
        case 4: in = Wk; out = oWk; n = NWE; break;
        case 5: in = Wv; out = oWv; n = NWE; break;
        default: in = Wo; out = oWo; n = NWE; break;
    }
    int i = (blockIdx.x * 256 + threadIdx.x) * 8;
    if (i < n) {
        float4 v0 = *reinterpret_cast<const float4*>(in + i);
        float4 v1 = *reinterpret_cast<const float4*>(in + i + 4);
        uint2 lo = pack4(v0.x, v0.y, v0.z, v0.w);
        uint2 hi = pack4(v1.x, v1.y, v1.z, v1.w);
        *reinterpret_cast<uint4*>(out + i) = make_uint4(lo.x, lo.y, hi.x, hi.y);
    }
}

// rvT[d][kperm(c)] = rv[c+1][d] bf16 (c in [0,256)); rkb zero-padded to 272 rows
__global__ __launch_bounds__(256)
void prep_tables(const float* __restrict__ rv, const float* __restrict__ rk,
                 ushort_t* __restrict__ rvT, ushort_t* __restrict__ rkb)
{
    int idx = blockIdx.x * 256 + threadIdx.x;
    if (idx < 64 * 256) {
        int d = idx >> 8, c = idx & 255;
        rvT[d * 256 + kperm(c)] = f2bf(rv[(size_t)(c + 1) * DH + d]);
    }
    idx -= 64 * 256;
    if (idx >= 0 && idx < 272 * 64) {
        int j = idx >> 6, d2 = idx & 63;
        rkb[idx] = (j < NREL) ? f2bf(rk[(size_t)j * DH + d2]) : (ushort_t)0;
    }
}

// ---------------------------------------------------------------------------
// Merged Q/K/V projection GEMM, one launch (z selects slice; z==2 -> V mode).
// 128x64 tile, BK=32, 4 waves, gl_lds width-16 staging.
// ---------------------------------------------------------------------------
__global__ __launch_bounds__(256)
void gemm_qkv(const ushort_t* __restrict__ qbf, const ushort_t* __restrict__ kbf,
              const ushort_t* __restrict__ vbf, const ushort_t* __restrict__ Wqb,
              const ushort_t* __restrict__ Wkb, const ushort_t* __restrict__ Wvb,
              const float* __restrict__ bq, const float* __restrict__ bk,
              const float* __restrict__ bv, ushort_t* __restrict__ qhb,
              ushort_t* __restrict__ khb, ushort_t* __restrict__ vtb)
{
    __shared__ ushort_t As[128 * 32];
    __shared__ ushort_t Bs[64 * 32];
    const int z = blockIdx.z;
    const ushort_t* A = z == 0 ? qbf : (z == 1 ? kbf : vbf);
    const ushort_t* W = z == 0 ? Wqb : (z == 1 ? Wkb : Wvb);
    const float* bias = z == 0 ? bq : (z == 1 ? bk : bv);
    ushort_t* dst     = z == 0 ? qhb : (z == 1 ? khb : vtb);
    const bool vmode  = (z == 2);
    const int K = EM;

    const int t = threadIdx.x, lane = t & 63;
    const int wv = t >> 6, wr = wv >> 1, wc = wv & 1;
    const int g = lane >> 4, c16 = lane & 15;
    const int rowi = lane >> 2, chi = lane & 3;   // staging: 16 rows x 4 chunks

    const int nwg = gridDim.x * gridDim.y;        // 512 per slice
    int flat = blockIdx.y * gridDim.x + blockIdx.x;
    int rm = (flat & 7) * (nwg >> 3) + (flat >> 3);
    const int n0 = (rm % gridDim.x) * 64;
    const int m0 = (rm / gridDim.x) * 128;

    f32x4 acc[4][2];
#pragma unroll
    for (int i = 0; i < 4; ++i)
#pragma unroll
        for (int j = 0; j < 2; ++j) acc[i][j] = (f32x4){0.f, 0.f, 0.f, 0.f};

    for (int k0 = 0; k0 < K; k0 += 32) {
        __syncthreads();
#pragma unroll
        for (int j = 0; j < 2; ++j) {
            const int rbase = wv * 32 + j * 16;   // wave-uniform A rows
            gl_lds16(A + (size_t)(m0 + rbase + rowi) * K + k0 + chi * 8,
                     As + rbase * 32);
        }
        {
            const int rbase = wv * 16;            // wave-uniform B rows
            gl_lds16(W + (size_t)(n0 + rbase + rowi) * K + k0 + chi * 8,
                     Bs + rbase * 32);
        }
        __syncthreads();

        bf16x8 af[4], bfr[2];
#pragma unroll
        for (int i = 0; i < 4; ++i)
            af[i] = *reinterpret_cast<const bf16x8*>(As + (wr * 64 + i * 16 + c16) * 32 + g * 8);
#pragma unroll
        for (int j = 0; j < 2; ++j)
            bfr[j] = *reinterpret_cast<const bf16x8*>(Bs + (wc * 32 + j * 16 + c16) * 32 + g * 8);
#pragma unroll
        for (int i = 0; i < 4; ++i)
#pragma unroll
            for (int j = 0; j < 2; ++j)
                acc[i][j] = MFMA16(af[i], bfr[j], acc[i][j]);
    }

#pragma unroll
    for (int j = 0; j < 2; ++j) {
        const int n = n0 + wc * 32 + j * 16 + c16;
        const float bn = bias[n];
#pragma unroll
        for (int i = 0; i < 4; ++i) {
#pragma unroll
            for (int r = 0; r < 4; ++r) {
                const int m = m0 + wr * 64 + i * 16 + 4 * g + r;
                const float vv = acc[i][j][r] + bn;
                const int b = m >> 11, s = m & (SQ - 1);
                const int h = n >> 6, dd = n & 63;
                if (!vmode) {
                    dst[(((size_t)b * NH + h) * SQ + s) * DH + dd] = f2bf(vv);
                } else {
                    const int sp = kperm(s);
                    dst[(((size_t)b * NH + h) * DH + dd) * SQ + sp] = f2bf(vv);
                }
            }
        }
    }
}

// ---------------------------------------------------------------------------
// Final output GEMM: f32 dst = A @ W^T + bias; 128x64 tile.
// ---------------------------------------------------------------------------
__global__ __launch_bounds__(256)
void gemm_out(const ushort_t* __restrict__ A, const ushort_t* __restrict__ W,
              const float* __restrict__ bias, float* __restrict__ dst,
              int M, int N, int K)
{
    __shared__ ushort_t As[128 * 32];
    __shared__ ushort_t Bs[64 * 32];
    const int t = threadIdx.x, lane = t & 63;
    const int wv = t >> 6, wr = wv >> 1, wc = wv & 1;
    const int g = lane >> 4, c16 = lane & 15;
    const int rowi = lane >> 2, chi = lane & 3;

    const int nwg = gridDim.x * gridDim.y;
    int flat = blockIdx.y * gridDim.x + blockIdx.x;
    int rm = (flat & 7) * (nwg >> 3) + (flat >> 3);
    const int n0 = (rm % gridDim.x) * 64;
    const int m0 = (rm / gridDim.x) * 128;

    f32x4 acc[4][2];
#pragma unroll
    for (int i = 0; i < 4; ++i)
#pragma unroll
        for (int j = 0; j < 2; ++j) acc[i][j] = (f32x4){0.f, 0.f, 0.f, 0.f};

    for (int k0 = 0; k0 < K; k0 += 32) {
        __syncthreads();
#pragma unroll
        for (int j = 0; j < 2; ++j) {
            const int rbase = wv * 32 + j * 16;
            gl_lds16(A + (size_t)(m0 + rbase + rowi) * K + k0 + chi * 8,
                     As + rbase * 32);
        }
        {
            const int rbase = wv * 16;
            gl_lds16(W + (size_t)(n0 + rbase + rowi) * K + k0 + chi * 8,
                     Bs + rbase * 32);
        }
        __syncthreads();

        bf16x8 af[4], bfr[2];
#pragma unroll
        for (int i = 0; i < 4; ++i)
            af[i] = *reinterpret_cast<const bf16x8*>(As + (wr * 64 + i * 16 + c16) * 32 + g * 8);
#pragma unroll
        for (int j = 0; j < 2; ++j)
            bfr[j] = *reinterpret_cast<const bf16x8*>(Bs + (wc * 32 + j * 16 + c16) * 32 + g * 8);
#pragma unroll
        for (int i = 0; i < 4; ++i)
#pragma unroll
            for (int j = 0; j < 2; ++j)
                acc[i][j] = MFMA16(af[i], bfr[j], acc[i][j]);
    }

#pragma unroll
    for (int j = 0; j < 2; ++j) {
        const int n = n0 + wc * 32 + j * 16 + c16;
        const float bn = bias[n];
#pragma unroll
        for (int i = 0; i < 4; ++i)
#pragma unroll
            for (int r = 0; r < 4; ++r) {
                const int m = m0 + wr * 64 + i * 16 + 4 * g + r;
                dst[(size_t)m * N + n] = acc[i][j][r] + bn;
            }
    }
}

// ---------------------------------------------------------------------------
// qrel[r][j] = dot(qh[r], rk[j]) * SCL, bf16 out, stride QSTR.
// ---------------------------------------------------------------------------
__global__ __launch_bounds__(256)
void qrel_mfma(const ushort_t* __restrict__ qh, const ushort_t* __restrict__ rkb,
               ushort_t* __restrict__ qrel)
{
    const int t = threadIdx.x, lane = t & 63, w = t >> 6;
    const int g = lane >> 4, c16 = lane & 15;
    const size_t r0 = (size_t)blockIdx.x * 64 + w * 16;

    bf16x8 af[2];
#pragma unroll
    for (int ks = 0; ks < 2; ++ks)
        af[ks] = *reinterpret_cast<const bf16x8*>(qh + (r0 + c16) * DH + ks * 32 + g * 8);

    f32x4 acc[17];
#pragma unroll
    for (int n = 0; n < 17; ++n) acc[n] = (f32x4){0.f, 0.f, 0.f, 0.f};
#pragma unroll
    for (int n = 0; n < 17; ++n)
#pragma unroll
        for (int ks = 0; ks < 2; ++ks) {
            bf16x8 bf = *reinterpret_cast<const bf16x8*>(
                rkb + (size_t)(16 * n + c16) * DH + ks * 32 + g * 8);
            acc[n] = MFMA16(af[ks], bf, acc[n]);
        }
#pragma unroll
    for (int n = 0; n < 17; ++n) {
        const int j = 16 * n + c16;
        if (j < NREL) {
#pragma unroll
            for (int r = 0; r < 4; ++r)
                qrel[(r0 + 4 * g + r) * QSTR + j] = f2bf(acc[n][r] * SCL);
        }
    }
}

// ---------------------------------------------------------------------------
// Flash attention (round-14 form, best measured): QBLK=64, single-tile
// staging with reg prefetch, 2 barriers/tile, stride-72 linear LDS.
// w1 = P@V (kappa-space), lac/b0/b256; band P tiles (5/q-block) -> Ptile.
// ---------------------------------------------------------------------------
__global__ __launch_bounds__(256, 4)
void attn_flash(const ushort_t* __restrict__ qh, const ushort_t* __restrict__ kh,
                const ushort_t* __restrict__ vt, const ushort_t* __restrict__ qrel,
                ushort_t* __restrict__ Ptile, float* __restrict__ w1g,
                float* __restrict__ lacg, float* __restrict__ b0g,
                float* __restrict__ b256g)
{
    __shared__ ushort_t Ks[64 * 72];
    __shared__ ushort_t Vs[64 * 72];
    __shared__ ushort_t PQs[64 * 72];   // Q at start, then P (kappa cols)

    const int t = threadIdx.x, lane = t & 63, w = t >> 6;
    const int g = lane >> 4, c16 = lane & 15;
    const int nwg = gridDim.x * gridDim.y;
    int flat = blockIdx.y * gridDim.x + blockIdx.x;
    int rmid = (flat & 7) * (nwg >> 3) + (flat >> 3);
    const int q0 = (rmid & 31) * 64;
    const int bh = rmid >> 5;
    const size_t Gbase = ((size_t)bh * 32 + (q0 >> 6)) * 5;

    // stage Q -> LDS -> register fragments
#pragma unroll
    for (int l = 0; l < 2; ++l) {
        const int fid = t + 256 * l;
        const int row = fid >> 3, ch = fid & 7;
        uint4 v = *reinterpret_cast<const uint4*>(
            qh + ((size_t)bh * SQ + q0 + row) * DH + ch * 8);
        *reinterpret_cast<uint4*>(PQs + row * 72 + ch * 8) = v;
    }
    __syncthreads();
    bf16x8 qf[2];
#pragma unroll
    for (int ks = 0; ks < 2; ++ks)
        qf[ks] = *reinterpret_cast<const bf16x8*>(PQs + (w * 16 + c16) * 72 + ks * 32 + g * 8);

    const ushort_t* qrb = qrel + ((size_t)bh * SQ + q0) * QSTR;
    float q0add[4], q256add[4];
#pragma unroll
    for (int i = 0; i < 4; ++i) {
        const int r = w * 16 + 4 * g + i;
        q0add[i]   = bf2f(qrb[(size_t)r * QSTR + 0]);
        q256add[i] = bf2f(qrb[(size_t)r * QSTR + 256]);
    }

    f32x4 w1[4];
#pragma unroll
    for (int n = 0; n < 4; ++n) w1[n] = (f32x4){0.f, 0.f, 0.f, 0.f};
    float lac[4] = {0.f,0.f,0.f,0.f}, b0[4] = {0.f,0.f,0.f,0.f}, b256[4] = {0.f,0.f,0.f,0.f};

    // pipelined staging registers
    const int row_l = t >> 3, ch_l = t & 7;
    const int row_h = row_l + 32;
    uint4 kr0, kr1, vr0, vr1;
    {
        kr0 = *reinterpret_cast<const uint4*>(kh + ((size_t)bh * SQ + row_l) * DH + ch_l * 8);
        kr1 = *reinterpret_cast<const uint4*>(kh + ((size_t)bh * SQ + row_h) * DH + ch_l * 8);
        vr0 = *reinterpret_cast<const uint4*>(vt + ((size_t)bh * DH + row_l) * SQ + ch_l * 8);
        vr1 = *reinterpret_cast<const uint4*>(vt + ((size_t)bh * DH + row_h) * SQ + ch_l * 8);
    }

    for (int k0 = 0; k0 < SQ; k0 += 64) {
        __syncthreads();   // prev tile's MFMA LDS reads done (also covers qf loads)
        *reinterpret_cast<uint4*>(Ks + row_l * 72 + ch_l * 8) = kr0;
        *reinterpret_cast<uint4*>(Ks + row_h * 72 + ch_l * 8) = kr1;
        *reinterpret_cast<uint4*>(Vs + row_l * 72 + ch_l * 8) = vr0;
        *reinterpret_cast<uint4*>(Vs + row_h * 72 + ch_l * 8) = vr1;
        __syncthreads();
        if (k0 + 64 < SQ) {   // prefetch next tile; latency hidden by compute
            kr0 = *reinterpret_cast<const uint4*>(kh + ((size_t)bh * SQ + k0 + 64 + row_l) * DH + ch_l * 8);
            kr1 = *reinterpret_cast<const uint4*>(kh + ((size_t)bh * SQ + k0 + 64 + row_h) * DH + ch_l * 8);
            vr0 = *reinterpret_cast<const uint4*>(vt + ((size_t)bh * DH + row_l) * SQ + k0 + 64 + ch_l * 8);
            vr1 = *reinterpret_cast<const uint4*>(vt + ((size_t)bh * DH + row_h) * SQ + k0 + 64 + ch_l * 8);
        }

        f32x4 s[4];
#pragma unroll
        for (int n = 0; n < 4; ++n) s[n] = (f32x4){0.f, 0.f, 0.f, 0.f};
        __builtin_amdgcn_s_setprio(1);
#pragma unroll
        for (int ks = 0; ks < 2; ++ks)
#pragma unroll
            for (int n = 0; n < 4; ++n) {
                bf16x8 kf = *reinterpret_cast<const bf16x8*>(
                    Ks + (16 * n + c16) * 72 + ks * 32 + g * 8);
                s[n] = MFMA16(qf[ks], kf, s[n]);
            }
        __builtin_amdgcn_s_setprio(0);

        const int rel0 = k0 - q0;
        float rsum[4] = {0.f, 0.f, 0.f, 0.f};
        if (rel0 <= -192 || rel0 >= 192) {                 // far: uniform bias
            const bool lo = rel0 < 0;
#pragma unroll
            for (int i = 0; i < 4; ++i) {
                const float add = lo ? q0add[i] : q256add[i];
#pragma unroll
                for (int n = 0; n < 4; ++n) {
                    const float p = exp2f(fmaf(s[n][i], SCL, add));
                    s[n][i] = p; rsum[i] += p;
                }
                if (lo) b0[i] += rsum[i]; else b256[i] += rsum[i];
                const int qloc = w * 16 + 4 * g + i;
                *reinterpret_cast<uint2*>(PQs + qloc * 72 + c16 * 4) =
                    pack4(s[0][i], s[1][i], s[2][i], s[3][i]);
            }
        } else if (rel0 == -128 || rel0 == 128) {          // mixed band edge
            const int tix = (rel0 + 128) >> 6;
#pragma unroll
            for (int i = 0; i < 4; ++i) {
                const int qloc = w * 16 + 4 * g + i;
                const ushort_t* qrow = qrb + (size_t)qloc * QSTR;
                float z[4];
#pragma unroll
                for (int n = 0; n < 4; ++n) {
                    const int rel = rel0 + 16 * n + c16 - qloc;
                    const int idx = rel < -128 ? 0 : (rel > 128 ? 256 : rel + 128);
                    const float p = exp2f(fmaf(s[n][i], SCL, bf2f(qrow[idx])));
                    s[n][i] = p; rsum[i] += p;
                    const bool inb = (rel >= -127) & (rel <= 127);
                    z[n] = inb ? p : 0.f;
                    if (rel <= -128)      b0[i] += p;
                    else if (rel >= 128)  b256[i] += p;
                }
                *reinterpret_cast<uint2*>(PQs + qloc * 72 + c16 * 4) =
                    pack4(s[0][i], s[1][i], s[2][i], s[3][i]);
                *reinterpret_cast<uint2*>(
                    Ptile + ((Gbase + tix) * 64 + qloc) * 64 + 4 * c16) =
                    pack4(z[0], z[1], z[2], z[3]);
            }
        } else {                                           // pure band: no clamp
            const int tix = (rel0 + 128) >> 6;
#pragma unroll
            for (int i = 0; i < 4; ++i) {
                const int qloc = w * 16 + 4 * g + i;
                const ushort_t* qrow = qrb + (size_t)qloc * QSTR;
#pragma unroll
                for (int n = 0; n < 4; ++n) {
                    const int rel = rel0 + 16 * n + c16 - qloc;
                    const float p = exp2f(fmaf(s[n][i], SCL, bf2f(qrow[rel + 128])));
                    s[n][i] = p; rsum[i] += p;
                }
                const uint2 pk = pack4(s[0][i], s[1][i], s[2][i], s[3][i]);
                *reinterpret_cast<uint2*>(PQs + qloc * 72 + c16 * 4) = pk;
                *reinterpret_cast<uint2*>(
                    Ptile + ((Gbase + tix) * 64 + qloc) * 64 + 4 * c16) = pk;
            }
        }
#pragma unroll
        for (int i = 0; i < 4; ++i) lac[i] += rsum[i];

        // w1 += P @ V
        __builtin_amdgcn_s_setprio(1);
#pragma unroll
        for (int ks = 0; ks < 2; ++ks) {
            bf16x8 pf = *reinterpret_cast<const bf16x8*>(
                PQs + (w * 16 + c16) * 72 + ks * 32 + g * 8);
#pragma unroll
            for (int n = 0; n < 4; ++n) {
                bf16x8 vf = *reinterpret_cast<const bf16x8*>(
                    Vs + (16 * n + c16) * 72 + ks * 32 + g * 8);
                w1[n] = MFMA16(pf, vf, w1[n]);
            }
        }
        __builtin_amdgcn_s_setprio(0);
    }

#pragma unroll
    for (int m = 1; m < 16; m <<= 1)
#pragma unroll
        for (int i = 0; i < 4; ++i) {
            lac[i]  += __shfl_xor(lac[i],  m, 64);
            b0[i]   += __shfl_xor(b0[i],   m, 64);
            b256[i] += __shfl_xor(b256[i], m, 64);
        }
    if (c16 == 0) {
#pragma unroll
        for (int i = 0; i < 4; ++i) {
            const size_t row = (size_t)bh * SQ + q0 + w * 16 + 4 * g + i;
            lacg[row] = lac[i]; b0g[row] = b0[i]; b256g[row] = b256[i];
        }
    }
#pragma unroll
    for (int n = 0; n < 4; ++n)
#pragma unroll
        for (int i = 0; i < 4; ++i) {
            const size_t row = (size_t)bh * SQ + q0 + w * 16 + 4 * g + i;
            w1g[row * DH + 16 * n + c16] = w1[n][i];
        }
}

// ---------------------------------------------------------------------------
// Band GEMM + combine: scatter 5 P tiles into shifted LDS layout
// Pband[q][kperm(rel+127)] (bucket 255 = b256 mass), w2 = Pband @ rvT^T,
// out = (w1 + w2 + b0*rv[0]) / lac -> wbuf [B,S,H,D] bf16.
// ---------------------------------------------------------------------------
__global__ __launch_bounds__(256)
void band_gemm(const ushort_t* __restrict__ Ptile, const ushort_t* __restrict__ rvT,
               const float* __restrict__ rv_f32, const float* __restrict__ w1g,
               const float* __restrict__ lacg, const float* __restrict__ b0g,
               const float* __restrict__ b256g, ushort_t* __restrict__ wout)
{
    __shared__ ushort_t Pband[64 * 264];
    const int t = threadIdx.x, lane = t & 63, w = t >> 6;
    const int g = lane >> 4, c16 = lane & 15;
    const int G = blockIdx.x;             // q-block id (= bh*32 + qb)
    const size_t r0 = (size_t)G * 64;
    const int q0 = (G & 31) * 64;

    for (int i = t; i < 64 * 264 / 2; i += 256)
        reinterpret_cast<unsigned*>(Pband)[i] = 0u;
    __syncthreads();

    // scatter tiles (coalesced reads, LDS b16 scatter)
    for (int u = t; u < 5 * 64 * 16; u += 256) {
        const int tix = u >> 10;
        const int kt0 = q0 + (tix - 2) * 64;
        if (kt0 < 0 || kt0 >= SQ) continue;
        const int qloc = (u >> 4) & 63;
        const int c = u & 15;
        uint2 pv = *reinterpret_cast<const uint2*>(
            Ptile + (((size_t)G * 5 + tix) * 64 + qloc) * 64 + 4 * c);
        const ushort_t* pe = reinterpret_cast<const ushort_t*>(&pv);
        const int relbase = (tix - 2) * 64 - qloc + 127;
#pragma unroll
        for (int n = 0; n < 4; ++n) {
            const int x = relbase + 16 * n + c;
            if (x >= 0 && x <= 254)
                Pband[qloc * 264 + ((x & ~63) | ((x & 15) << 2) | ((x >> 4) & 3))] = pe[n];
        }
    }
    if (t < 64) Pband[t * 264 + 255] = f2bf(b256g[r0 + t]);
    __syncthreads();

    f32x4 acc[4];
#pragma unroll
    for (int n = 0; n < 4; ++n) acc[n] = (f32x4){0.f, 0.f, 0.f, 0.f};
#pragma unroll
    for (int ks = 0; ks < 8; ++ks) {
        bf16x8 pm = *reinterpret_cast<const bf16x8*>(
            Pband + (w * 16 + c16) * 264 + ks * 32 + g * 8);
#pragma unroll
        for (int n = 0; n < 4; ++n) {
            bf16x8 rf = *reinterpret_cast<const bf16x8*>(
                rvT + (size_t)(16 * n + c16) * 256 + ks * 32 + g * 8);
            acc[n] = MFMA16(pm, rf, acc[n]);
        }
    }

#pragma unroll
    for (int i = 0; i < 4; ++i) {
        const size_t row = r0 + w * 16 + 4 * g + i;
        const float inv = 1.0f / lacg[row];
        const float vb0 = b0g[row];
        const int b = (int)(row >> 15), h = (int)((row >> 11) & 15), s = (int)(row & 2047);
#pragma unroll
        for (int n = 0; n < 4; ++n) {
            const int col = 16 * n + c16;
            const float val = (w1g[row * DH + col] + acc[n][i] + vb0 * rv_f32[col]) * inv;
            wout[(((size_t)b * SQ + s) * NH + h) * DH + col] = f2bf(val);
        }
    }
}

// ---------------------------------------------------------------------------
extern "C" void kernel_launch(void* const* d_in, const int* in_sizes, int n_in,
                              void* d_out, int out_size, void* d_ws, size_t ws_size,
                              hipStream_t stream)
{
    const float* q  = (const float*)d_in[0];
    const float* k  = (const float*)d_in[1];
    const float* v  = (const float*)d_in[2];
    const float* Wq = (const float*)d_in[3];
    const float* bq = (const float*)d_in[4];
    const float* Wk = (const float*)d_in[5];
    const float* bk = (const float*)d_in[6];
    const float* Wv = (const float*)d_in[7];
    const float* bv = (const float*)d_in[8];
    const float* Wo = (const float*)d_in[9];
    const float* bo = (const float*)d_in[10];
    const float* rk = (const float*)d_in[11];
    const float* rv = (const float*)d_in[12];

    char* ws = (char*)d_ws;
    auto alloc = [&](size_t bytes) { char* p = ws; ws += bytes; return p; };
    const size_t QB = (size_t)NB * SQ * EM * 2;       // 8 MB
    const size_t WB = (size_t)EM * EM * 2;            // 2 MB

    // Ptile aliases the early bf16 staging buffers (dead before flash runs).
    char* region0 = alloc(NR * 320 * 2);              // 41.9 MB
    ushort_t* Ptile = (ushort_t*)region0;             // [NR/64][5][64][64]
    ushort_t* qbf = (ushort_t*)region0;
    ushort_t* kbf = (ushort_t*)(region0 + QB);
    ushort_t* vbf = (ushort_t*)(region0 + 2 * QB);
    ushort_t* Wqb = (ushort_t*)(region0 + 3 * QB);
    ushort_t* Wkb = (ushort_t*)(region0 + 3 * QB + WB);
    ushort_t* Wvb = (ushort_t*)(region0 + 3 * QB + 2 * WB);   // ends at 30 MB < 41.9

    ushort_t* Wob  = (ushort_t*)alloc(WB);            // survives until final GEMM
    ushort_t* qhb  = (ushort_t*)alloc(QB);            // [B,H,S,D]
    ushort_t* khb  = (ushort_t*)alloc(QB);            // [B,H,S,D]
    ushort_t* vtb  = (ushort_t*)alloc(QB);            // [B,H,D,S'] kappa-permuted
    ushort_t* wbuf = (ushort_t*)alloc(QB);            // [B,S,H,D]
    ushort_t* rvT  = (ushort_t*)alloc(64 * 256 * 2);
    ushort_t* rkb  = (ushort_t*)alloc(272 * 64 * 2);
    ushort_t* qrel = (ushort_t*)alloc(NR * QSTR * 2);
    float*    w1g  = (float*)alloc(NR * DH * 4);
    float*    lacg = (float*)alloc(NR * 4);
    float*    b0g  = (float*)alloc(NR * 4);
    float*    b256g= (float*)alloc(NR * 4);

    cvt7<<<dim3(NQE / 2048, 7), 256, 0, stream>>>(
        q, k, v, Wq, Wk, Wv, Wo, qbf, kbf, vbf, Wqb, Wkb, Wvb, Wob);
    prep_tables<<<132, 256, 0, stream>>>(rv, rk, rvT, rkb);

    const int M = NB * SQ;
    gemm_qkv<<<dim3(EM / 64, M / 128, 3), 256, 0, stream>>>(
        qbf, kbf, vbf, Wqb, Wkb, Wvb, bq, bk, bv, qhb, khb, vtb);
    qrel_mfma<<<(int)(NR / 64), 256, 0, stream>>>(qhb, rkb, qrel);

    attn_flash<<<dim3(32, 32), 256, 0, stream>>>(qhb, khb, vtb, qrel,
                                                 Ptile, w1g, lacg, b0g, b256g);
    band_gemm<<<(int)(NR / 64), 256, 0, stream>>>(Ptile, rvT, rv, w1g, lacg,
                                                  b0g, b256g, wbuf);
    gemm_out<<<dim3(EM / 64, M / 128), 256, 0, stream>>>(
        wbuf, Wob, bo, (float*)d_out, M, EM, EM);
}

// Round 17
// 256.203 us; speedup vs baseline: 1.0380x; 1.0063x over previous
//
#include <hip/hip_runtime.h>
#include <hip/hip_bf16.h>
#include <cstdint>
#include <cstddef>

#define NH   16
#define DH   64
#define SQ   2048
#define NB   2
#define EM   1024
#define NREL 257
#define QSTR 258          // qrel row stride (elements)
#define SCL  0.18033688f  // 0.125 * log2(e)
#define NR   ((size_t)NB * NH * SQ)   // 65536 rows
#define NQE  (NB * SQ * EM)           // 4194304
#define NWE  (EM * EM)                // 1048576

typedef unsigned short ushort_t;
using bf16x8 = __attribute__((ext_vector_type(8))) __bf16;
using bf16x4 = __attribute__((ext_vector_type(4))) __bf16;
using f32x4  = __attribute__((ext_vector_type(4))) float;
#define MFMA16(a, b, c) __builtin_amdgcn_mfma_f32_16x16x32_bf16(a, b, c, 0, 0, 0)

__device__ __forceinline__ ushort_t f2bf(float f) {
    union { __bf16 h; ushort_t u; } x; x.h = (__bf16)f; return x.u;
}
__device__ __forceinline__ float bf2f(ushort_t u) {
    union { unsigned u; float f; } x; x.u = ((unsigned)u) << 16;
    return x.f;
}
__device__ __forceinline__ uint2 pack4(float a, float b, float c, float d) {
    union { bf16x4 v; uint2 u; } x;
    x.v = (bf16x4){ (__bf16)a, (__bf16)b, (__bf16)c, (__bf16)d };
    return x.u;
}
// kappa permutation within a 64-block: k = 16n + c16  ->  kap = 4*c16 + n
__device__ __forceinline__ int kperm(int x) {
    return (x & ~63) | ((x & 15) << 2) | ((x >> 4) & 3);
}
// HBM -> LDS direct, 16B per lane (lane l lands at ldsbase + l*16)
__device__ __forceinline__ void gl_lds16(const void* g, void* l) {
    __builtin_amdgcn_global_load_lds(
        (const __attribute__((address_space(1))) unsigned int*)g,
        (__attribute__((address_space(3))) unsigned int*)l, 16, 0, 0);
}

// ---------------------------------------------------------------------------
// single-launch prep: f32->bf16 converts for all 7 arrays (y = 0..6) and
// table prep (y = 7: rvT kappa-transposed, rkb zero-padded).
// ---------------------------------------------------------------------------
__global__ __launch_bounds__(256)
void cvt8(const float* __restrict__ q, const float* __restrict__ k,
          const float* __restrict__ v, const float* __restrict__ Wq,
          const float* __restrict__ Wk, const float* __restrict__ Wv,
          const float* __restrict__ Wo, const float* __restrict__ rv,
          const float* __restrict__ rk,
          ushort_t* __restrict__ oq, ushort_t* __restrict__ ok,
          ushort_t* __restrict__ ov, ushort_t* __restrict__ oWq,
          ushort_t* __restrict__ oWk, ushort_t* __restrict__ oWv,
          ushort_t* __restrict__ oWo, ushort_t* __restrict__ rvT,
          ushort_t* __restrict__ rkb)
{
    const int y = blockIdx.y;
    if (y == 7) {   // table prep (first 132 blocks do work)
        int idx = blockIdx.x * 256 + threadIdx.x;
        if (idx < 64 * 256) {
            int d = idx >> 8, c = idx & 255;
            rvT[d * 256 + kperm(c)] = f2bf(rv[(size_t)(c + 1) * DH + d]);
        }
        idx -= 64 * 256;
        if (idx >= 0 && idx < 272 * 64) {
            int j = idx >> 6, d2 = idx & 63;
            rkb[idx] = (j < NREL) ? f2bf(rk[(size_t)j * DH + d2]) : (ushort_t)0;
        }
        return;
    }
    const float* in; ushort_t* out; int n;
    switch (y) {
        case 0: in = q;  out = oq;  n = NQE; break;
        case 1: in = k;  out = ok;  n = NQE; break;
        case 2: in = v;  out = ov;  n = NQE; break;
        case 3: in = Wq; out = oWq; n = NWE; break;
        case 4: in = Wk; out = oWk; n = NWE; break;
        case 5: in = Wv; out = oWv; n = NWE; break;
        default: in = Wo; out = oWo; n = NWE; break;
    }
    int i = (blockIdx.x * 256 + threadIdx.x) * 8;
    if (i < n) {
        float4 v0 = *reinterpret_cast<const float4*>(in + i);
        float4 v1 = *reinterpret_cast<const float4*>(in + i + 4);
        uint2 lo = pack4(v0.x, v0.y, v0.z, v0.w);
        uint2 hi = pack4(v1.x, v1.y, v1.z, v1.w);
        *reinterpret_cast<uint4*>(out + i) = make_uint4(lo.x, lo.y, hi.x, hi.y);
    }
}

// ---------------------------------------------------------------------------
// Merged Q/K/V projection GEMM, one launch (z selects slice; z==2 -> V mode).
// 128x64 tile, BK=32, 4 waves, gl_lds width-16 staging.
// ---------------------------------------------------------------------------
__global__ __launch_bounds__(256)
void gemm_qkv(const ushort_t* __restrict__ qbf, const ushort_t* __restrict__ kbf,
              const ushort_t* __restrict__ vbf, const ushort_t* __restrict__ Wqb,
              const ushort_t* __restrict__ Wkb, const ushort_t* __restrict__ Wvb,
              const float* __restrict__ bq, const float* __restrict__ bk,
              const float* __restrict__ bv, ushort_t* __restrict__ qhb,
              ushort_t* __restrict__ khb, ushort_t* __restrict__ vtb)
{
    __shared__ ushort_t As[128 * 32];
    __shared__ ushort_t Bs[64 * 32];
    const int z = blockIdx.z;
    const ushort_t* A = z == 0 ? qbf : (z == 1 ? kbf : vbf);
    const ushort_t* W = z == 0 ? Wqb : (z == 1 ? Wkb : Wvb);
    const float* bias = z == 0 ? bq : (z == 1 ? bk : bv);
    ushort_t* dst     = z == 0 ? qhb : (z == 1 ? khb : vtb);
    const bool vmode  = (z == 2);
    const int K = EM;

    const int t = threadIdx.x, lane = t & 63;
    const int wv = t >> 6, wr = wv >> 1, wc = wv & 1;
    const int g = lane >> 4, c16 = lane & 15;
    const int rowi = lane >> 2, chi = lane & 3;   // staging: 16 rows x 4 chunks

    const int nwg = gridDim.x * gridDim.y;        // 512 per slice
    int flat = blockIdx.y * gridDim.x + blockIdx.x;
    int rm = (flat & 7) * (nwg >> 3) + (flat >> 3);
    const int n0 = (rm % gridDim.x) * 64;
    const int m0 = (rm / gridDim.x) * 128;

    f32x4 acc[4][2];
#pragma unroll
    for (int i = 0; i < 4; ++i)
#pragma unroll
        for (int j = 0; j < 2; ++j) acc[i][j] = (f32x4){0.f, 0.f, 0.f, 0.f};

    for (int k0 = 0; k0 < K; k0 += 32) {
        __syncthreads();
#pragma unroll
        for (int j = 0; j < 2; ++j) {
            const int rbase = wv * 32 + j * 16;   // wave-uniform A rows
            gl_lds16(A + (size_t)(m0 + rbase + rowi) * K + k0 + chi * 8,
                     As + rbase * 32);
        }
        {
            const int rbase = wv * 16;            // wave-uniform B rows
            gl_lds16(W + (size_t)(n0 + rbase + rowi) * K + k0 + chi * 8,
                     Bs + rbase * 32);
        }
        __syncthreads();

        bf16x8 af[4], bfr[2];
#pragma unroll
        for (int i = 0; i < 4; ++i)
            af[i] = *reinterpret_cast<const bf16x8*>(As + (wr * 64 + i * 16 + c16) * 32 + g * 8);
#pragma unroll
        for (int j = 0; j < 2; ++j)
            bfr[j] = *reinterpret_cast<const bf16x8*>(Bs + (wc * 32 + j * 16 + c16) * 32 + g * 8);
#pragma unroll
        for (int i = 0; i < 4; ++i)
#pragma unroll
            for (int j = 0; j < 2; ++j)
                acc[i][j] = MFMA16(af[i], bfr[j], acc[i][j]);
    }

#pragma unroll
    for (int j = 0; j < 2; ++j) {
        const int n = n0 + wc * 32 + j * 16 + c16;
        const float bn = bias[n];
#pragma unroll
        for (int i = 0; i < 4; ++i) {
#pragma unroll
            for (int r = 0; r < 4; ++r) {
                const int m = m0 + wr * 64 + i * 16 + 4 * g + r;
                const float vv = acc[i][j][r] + bn;
                const int b = m >> 11, s = m & (SQ - 1);
                const int h = n >> 6, dd = n & 63;
                if (!vmode) {
                    dst[(((size_t)b * NH + h) * SQ + s) * DH + dd] = f2bf(vv);
                } else {
                    const int sp = kperm(s);
                    dst[(((size_t)b * NH + h) * DH + dd) * SQ + sp] = f2bf(vv);
                }
            }
        }
    }
}

// ---------------------------------------------------------------------------
// Final output GEMM: f32 dst = A @ W^T + bias; 128x64 tile.
// ---------------------------------------------------------------------------
__global__ __launch_bounds__(256)
void gemm_out(const ushort_t* __restrict__ A, const ushort_t* __restrict__ W,
              const float* __restrict__ bias, float* __restrict__ dst,
              int M, int N, int K)
{
    __shared__ ushort_t As[128 * 32];
    __shared__ ushort_t Bs[64 * 32];
    const int t = threadIdx.x, lane = t & 63;
    const int wv = t >> 6, wr = wv >> 1, wc = wv & 1;
    const int g = lane >> 4, c16 = lane & 15;
    const int rowi = lane >> 2, chi = lane & 3;

    const int nwg = gridDim.x * gridDim.y;
    int flat = blockIdx.y * gridDim.x + blockIdx.x;
    int rm = (flat & 7) * (nwg >> 3) + (flat >> 3);
    const int n0 = (rm % gridDim.x) * 64;
    const int m0 = (rm / gridDim.x) * 128;

    f32x4 acc[4][2];
#pragma unroll
    for (int i = 0; i < 4; ++i)
#pragma unroll
        for (int j = 0; j < 2; ++j) acc[i][j] = (f32x4){0.f, 0.f, 0.f, 0.f};

    for (int k0 = 0; k0 < K; k0 += 32) {
        __syncthreads();
#pragma unroll
        for (int j = 0; j < 2; ++j) {
            const int rbase = wv * 32 + j * 16;
            gl_lds16(A + (size_t)(m0 + rbase + rowi) * K + k0 + chi * 8,
                     As + rbase * 32);
        }
        {
            const int rbase = wv * 16;
            gl_lds16(W + (size_t)(n0 + rbase + rowi) * K + k0 + chi * 8,
                     Bs + rbase * 32);
        }
        __syncthreads();

        bf16x8 af[4], bfr[2];
#pragma unroll
        for (int i = 0; i < 4; ++i)
            af[i] = *reinterpret_cast<const bf16x8*>(As + (wr * 64 + i * 16 + c16) * 32 + g * 8);
#pragma unroll
        for (int j = 0; j < 2; ++j)
            bfr[j] = *reinterpret_cast<const bf16x8*>(Bs + (wc * 32 + j * 16 + c16) * 32 + g * 8);
#pragma unroll
        for (int i = 0; i < 4; ++i)
#pragma unroll
            for (int j = 0; j < 2; ++j)
                acc[i][j] = MFMA16(af[i], bfr[j], acc[i][j]);
    }

#pragma unroll
    for (int j = 0; j < 2; ++j) {
        const int n = n0 + wc * 32 + j * 16 + c16;
        const float bn = bias[n];
#pragma unroll
        for (int i = 0; i < 4; ++i)
#pragma unroll
            for (int r = 0; r < 4; ++r) {
                const int m = m0 + wr * 64 + i * 16 + 4 * g + r;
                dst[(size_t)m * N + n] = acc[i][j][r] + bn;
            }
    }
}

// ---------------------------------------------------------------------------
// qrel[r][j] = dot(qh[r], rk[j]) * SCL, bf16 out, stride QSTR.
// ---------------------------------------------------------------------------
__global__ __launch_bounds__(256)
void qrel_mfma(const ushort_t* __restrict__ qh, const ushort_t* __restrict__ rkb,
               ushort_t* __restrict__ qrel)
{
    const int t = threadIdx.x, lane = t & 63, w = t >> 6;
    const int g = lane >> 4, c16 = lane & 15;
    const size_t r0 = (size_t)blockIdx.x * 64 + w * 16;

    bf16x8 af[2];
#pragma unroll
    for (int ks = 0; ks < 2; ++ks)
        af[ks] = *reinterpret_cast<const bf16x8*>(qh + (r0 + c16) * DH + ks * 32 + g * 8);

    f32x4 acc[17];
#pragma unroll
    for (int n = 0; n < 17; ++n) acc[n] = (f32x4){0.f, 0.f, 0.f, 0.f};
#pragma unroll
    for (int n = 0; n < 17; ++n)
#pragma unroll
        for (int ks = 0; ks < 2; ++ks) {
            bf16x8 bf = *reinterpret_cast<const bf16x8*>(
                rkb + (size_t)(16 * n + c16) * DH + ks * 32 + g * 8);
            acc[n] = MFMA16(af[ks], bf, acc[n]);
        }
#pragma unroll
    for (int n = 0; n < 17; ++n) {
        const int j = 16 * n + c16;
        if (j < NREL) {
#pragma unroll
            for (int r = 0; r < 4; ++r)
                qrel[(r0 + 4 * g + r) * QSTR + j] = f2bf(acc[n][r] * SCL);
        }
    }
}

// ---------------------------------------------------------------------------
// Flash attention (round-14/16 form; setprio removed — 4-wave lockstep loop
// is the m190 null/negative case, not the m191 positive case).
// QBLK=64, single-tile staging with reg prefetch, 2 barriers/tile,
// stride-72 linear LDS. w1 = P@V (kappa-space), lac/b0/b256;
// band P tiles (5/q-block) -> Ptile.
// ---------------------------------------------------------------------------
__global__ __launch_bounds__(256, 4)
void attn_flash(const ushort_t* __restrict__ qh, const ushort_t* __restrict__ kh,
                const ushort_t* __restrict__ vt, const ushort_t* __restrict__ qrel,
                ushort_t* __restrict__ Ptile, float* __restrict__ w1g,
                float* __restrict__ lacg, float* __restrict__ b0g,
                float* __restrict__ b256g)
{
    __shared__ ushort_t Ks[64 * 72];
    __shared__ ushort_t Vs[64 * 72];
    __shared__ ushort_t PQs[64 * 72];   // Q at start, then P (kappa cols)

    const int t = threadIdx.x, lane = t & 63, w = t >> 6;
    const int g = lane >> 4, c16 = lane & 15;
    const int nwg = gridDim.x * gridDim.y;
    int flat = blockIdx.y * gridDim.x + blockIdx.x;
    int rmid = (flat & 7) * (nwg >> 3) + (flat >> 3);
    const int q0 = (rmid & 31) * 64;
    const int bh = rmid >> 5;
    const size_t Gbase = ((size_t)bh * 32 + (q0 >> 6)) * 5;

    // stage Q -> LDS -> register fragments
#pragma unroll
    for (int l = 0; l < 2; ++l) {
        const int fid = t + 256 * l;
        const int row = fid >> 3, ch = fid & 7;
        uint4 v = *reinterpret_cast<const uint4*>(
            qh + ((size_t)bh * SQ + q0 + row) * DH + ch * 8);
        *reinterpret_cast<uint4*>(PQs + row * 72 + ch * 8) = v;
    }
    __syncthreads();
    bf16x8 qf[2];
#pragma unroll
    for (int ks = 0; ks < 2; ++ks)
        qf[ks] = *reinterpret_cast<const bf16x8*>(PQs + (w * 16 + c16) * 72 + ks * 32 + g * 8);

    const ushort_t* qrb = qrel + ((size_t)bh * SQ + q0) * QSTR;
    float q0add[4], q256add[4];
#pragma unroll
    for (int i = 0; i < 4; ++i) {
        const int r = w * 16 + 4 * g + i;
        q0add[i]   = bf2f(qrb[(size_t)r * QSTR + 0]);
        q256add[i] = bf2f(qrb[(size_t)r * QSTR + 256]);
    }

    f32x4 w1[4];
#pragma unroll
    for (int n = 0; n < 4; ++n) w1[n] = (f32x4){0.f, 0.f, 0.f, 0.f};
    float lac[4] = {0.f,0.f,0.f,0.f}, b0[4] = {0.f,0.f,0.f,0.f}, b256[4] = {0.f,0.f,0.f,0.f};

    // pipelined staging registers
    const int row_l = t >> 3, ch_l = t & 7;
    const int row_h = row_l + 32;
    uint4 kr0, kr1, vr0, vr1;
    {
        kr0 = *reinterpret_cast<const uint4*>(kh + ((size_t)bh * SQ + row_l) * DH + ch_l * 8);
        kr1 = *reinterpret_cast<const uint4*>(kh + ((size_t)bh * SQ + row_h) * DH + ch_l * 8);
        vr0 = *reinterpret_cast<const uint4*>(vt + ((size_t)bh * DH + row_l) * SQ + ch_l * 8);
        vr1 = *reinterpret_cast<const uint4*>(vt + ((size_t)bh * DH + row_h) * SQ + ch_l * 8);
    }

    for (int k0 = 0; k0 < SQ; k0 += 64) {
        __syncthreads();   // prev tile's MFMA LDS reads done (also covers qf loads)
        *reinterpret_cast<uint4*>(Ks + row_l * 72 + ch_l * 8) = kr0;
        *reinterpret_cast<uint4*>(Ks + row_h * 72 + ch_l * 8) = kr1;
        *reinterpret_cast<uint4*>(Vs + row_l * 72 + ch_l * 8) = vr0;
        *reinterpret_cast<uint4*>(Vs + row_h * 72 + ch_l * 8) = vr1;
        __syncthreads();
        if (k0 + 64 < SQ) {   // prefetch next tile; latency hidden by compute
            kr0 = *reinterpret_cast<const uint4*>(kh + ((size_t)bh * SQ + k0 + 64 + row_l) * DH + ch_l * 8);
            kr1 = *reinterpret_cast<const uint4*>(kh + ((size_t)bh * SQ + k0 + 64 + row_h) * DH + ch_l * 8);
            vr0 = *reinterpret_cast<const uint4*>(vt + ((size_t)bh * DH + row_l) * SQ + k0 + 64 + ch_l * 8);
            vr1 = *reinterpret_cast<const uint4*>(vt + ((size_t)bh * DH + row_h) * SQ + k0 + 64 + ch_l * 8);
        }

        f32x4 s[4];
#pragma unroll
        for (int n = 0; n < 4; ++n) s[n] = (f32x4){0.f, 0.f, 0.f, 0.f};
#pragma unroll
        for (int ks = 0; ks < 2; ++ks)
#pragma unroll
            for (int n = 0; n < 4; ++n) {
                bf16x8 kf = *reinterpret_cast<const bf16x8*>(
                    Ks + (16 * n + c16) * 72 + ks * 32 + g * 8);
                s[n] = MFMA16(qf[ks], kf, s[n]);
            }

        const int rel0 = k0 - q0;
        float rsum[4] = {0.f, 0.f, 0.f, 0.f};
        if (rel0 <= -192 || rel0 >= 192) {                 // far: uniform bias
            const bool lo = rel0 < 0;
#pragma unroll
            for (int i = 0; i < 4; ++i) {
                const float add = lo ? q0add[i] : q256add[i];
#pragma unroll
                for (int n = 0; n < 4; ++n) {
                    const float p = exp2f(fmaf(s[n][i], SCL, add));
                    s[n][i] = p; rsum[i] += p;
                }
                if (lo) b0[i] += rsum[i]; else b256[i] += rsum[i];
                const int qloc = w * 16 + 4 * g + i;
                *reinterpret_cast<uint2*>(PQs + qloc * 72 + c16 * 4) =
                    pack4(s[0][i], s[1][i], s[2][i], s[3][i]);
            }
        } else if (rel0 == -128 || rel0 == 128) {          // mixed band edge
            const int tix = (rel0 + 128) >> 6;
#pragma unroll
            for (int i = 0; i < 4; ++i) {
                const int qloc = w * 16 + 4 * g + i;
                const ushort_t* qrow = qrb + (size_t)qloc * QSTR;
                float z[4];
#pragma unroll
                for (int n = 0; n < 4; ++n) {
                    const int rel = rel0 + 16 * n + c16 - qloc;
                    const int idx = rel < -128 ? 0 : (rel > 128 ? 256 : rel + 128);
                    const float p = exp2f(fmaf(s[n][i], SCL, bf2f(qrow[idx])));
                    s[n][i] = p; rsum[i] += p;
                    const bool inb = (rel >= -127) & (rel <= 127);
                    z[n] = inb ? p : 0.f;
                    if (rel <= -128)      b0[i] += p;
                    else if (rel >= 128)  b256[i] += p;
                }
                *reinterpret_cast<uint2*>(PQs + qloc * 72 + c16 * 4) =
                    pack4(s[0][i], s[1][i], s[2][i], s[3][i]);
                *reinterpret_cast<uint2*>(
                    Ptile + ((Gbase + tix) * 64 + qloc) * 64 + 4 * c16) =
                    pack4(z[0], z[1], z[2], z[3]);
            }
        } else {                                           // pure band: no clamp
            const int tix = (rel0 + 128) >> 6;
#pragma unroll
            for (int i = 0; i < 4; ++i) {
                const int qloc = w * 16 + 4 * g + i;
                const ushort_t* qrow = qrb + (size_t)qloc * QSTR;
#pragma unroll
                for (int n = 0; n < 4; ++n) {
                    const int rel = rel0 + 16 * n + c16 - qloc;
                    const float p = exp2f(fmaf(s[n][i], SCL, bf2f(qrow[rel + 128])));
                    s[n][i] = p; rsum[i] += p;
                }
                const uint2 pk = pack4(s[0][i], s[1][i], s[2][i], s[3][i]);
                *reinterpret_cast<uint2*>(PQs + qloc * 72 + c16 * 4) = pk;
                *reinterpret_cast<uint2*>(
                    Ptile + ((Gbase + tix) * 64 + qloc) * 64 + 4 * c16) = pk;
            }
        }
#pragma unroll
        for (int i = 0; i < 4; ++i) lac[i] += rsum[i];

        // w1 += P @ V
#pragma unroll
        for (int ks = 0; ks < 2; ++ks) {
            bf16x8 pf = *reinterpret_cast<const bf16x8*>(
                PQs + (w * 16 + c16) * 72 + ks * 32 + g * 8);
#pragma unroll
            for (int n = 0; n < 4; ++n) {
                bf16x8 vf = *reinterpret_cast<const bf16x8*>(
                    Vs + (16 * n + c16) * 72 + ks * 32 + g * 8);
                w1[n] = MFMA16(pf, vf, w1[n]);
            }
        }
    }

#pragma unroll
    for (int m = 1; m < 16; m <<= 1)
#pragma unroll
        for (int i = 0; i < 4; ++i) {
            lac[i]  += __shfl_xor(lac[i],  m, 64);
            b0[i]   += __shfl_xor(b0[i],   m, 64);
            b256[i] += __shfl_xor(b256[i], m, 64);
        }
    if (c16 == 0) {
#pragma unroll
        for (int i = 0; i < 4; ++i) {
            const size_t row = (size_t)bh * SQ + q0 + w * 16 + 4 * g + i;
            lacg[row] = lac[i]; b0g[row] = b0[i]; b256g[row] = b256[i];
        }
    }
#pragma unroll
    for (int n = 0; n < 4; ++n)
#pragma unroll
        for (int i = 0; i < 4; ++i) {
            const size_t row = (size_t)bh * SQ + q0 + w * 16 + 4 * g + i;
            w1g[row * DH + 16 * n + c16] = w1[n][i];
        }
}

// ---------------------------------------------------------------------------
// Band GEMM + combine: scatter 5 P tiles into shifted LDS layout
// Pband[q][kperm(rel+127)] (bucket 255 = b256 mass), w2 = Pband @ rvT^T,
// out = (w1 + w2 + b0*rv[0]) / lac -> wbuf [B,S,H,D] bf16.
// ---------------------------------------------------------------------------
__global__ __launch_bounds__(256)
void band_gemm(const ushort_t* __restrict__ Ptile, const ushort_t* __restrict__ rvT,
               const float* __restrict__ rv_f32, const float* __restrict__ w1g,
               const float* __restrict__ lacg, const float* __restrict__ b0g,
               const float* __restrict__ b256g, ushort_t* __restrict__ wout)
{
    __shared__ ushort_t Pband[64 * 264];
    const int t = threadIdx.x, lane = t & 63, w = t >> 6;
    const int g = lane >> 4, c16 = lane & 15;
    const int G = blockIdx.x;             // q-block id (= bh*32 + qb)
    const size_t r0 = (size_t)G * 64;
    const int q0 = (G & 31) * 64;

    for (int i = t; i < 64 * 264 / 2; i += 256)
        reinterpret_cast<unsigned*>(Pband)[i] = 0u;
    __syncthreads();

    // scatter tiles (coalesced reads, LDS b16 scatter)
    for (int u = t; u < 5 * 64 * 16; u += 256) {
        const int tix = u >> 10;
        const int kt0 = q0 + (tix - 2) * 64;
        if (kt0 < 0 || kt0 >= SQ) continue;
        const int qloc = (u >> 4) & 63;
        const int c = u & 15;
        uint2 pv = *reinterpret_cast<const uint2*>(
            Ptile + (((size_t)G * 5 + tix) * 64 + qloc) * 64 + 4 * c);
        const ushort_t* pe = reinterpret_cast<const ushort_t*>(&pv);
        const int relbase = (tix - 2) * 64 - qloc + 127;
#pragma unroll
        for (int n = 0; n < 4; ++n) {
            const int x = relbase + 16 * n + c;
            if (x >= 0 && x <= 254)
                Pband[qloc * 264 + ((x & ~63) | ((x & 15) << 2) | ((x >> 4) & 3))] = pe[n];
        }
    }
    if (t < 64) Pband[t * 264 + 255] = f2bf(b256g[r0 + t]);
    __syncthreads();

    f32x4 acc[4];
#pragma unroll
    for (int n = 0; n < 4; ++n) acc[n] = (f32x4){0.f, 0.f, 0.f, 0.f};
#pragma unroll
    for (int ks = 0; ks < 8; ++ks) {
        bf16x8 pm = *reinterpret_cast<const bf16x8*>(
            Pband + (w * 16 + c16) * 264 + ks * 32 + g * 8);
#pragma unroll
        for (int n = 0; n < 4; ++n) {
            bf16x8 rf = *reinterpret_cast<const bf16x8*>(
                rvT + (size_t)(16 * n + c16) * 256 + ks * 32 + g * 8);
            acc[n] = MFMA16(pm, rf, acc[n]);
        }
    }

#pragma unroll
    for (int i = 0; i < 4; ++i) {
        const size_t row = r0 + w * 16 + 4 * g + i;
        const float inv = 1.0f / lacg[row];
        const float vb0 = b0g[row];
        const int b = (int)(row >> 15), h = (int)((row >> 11) & 15), s = (int)(row & 2047);
#pragma unroll
        for (int n = 0; n < 4; ++n) {
            const int col = 16 * n + c16;
            const float val = (w1g[row * DH + col] + acc[n][i] + vb0 * rv_f32[col]) * inv;
            wout[(((size_t)b * SQ + s) * NH + h) * DH + col] = f2bf(val);
        }
    }
}

// ---------------------------------------------------------------------------
extern "C" void kernel_launch(void* const* d_in, const int* in_sizes, int n_in,
                              void* d_out, int out_size, void* d_ws, size_t ws_size,
                              hipStream_t stream)
{
    const float* q  = (const float*)d_in[0];
    const float* k  = (const float*)d_in[1];
    const float* v  = (const float*)d_in[2];
    const float* Wq = (const float*)d_in[3];
    const float* bq = (const float*)d_in[4];
    const float* Wk = (const float*)d_in[5];
    const float* bk = (const float*)d_in[6];
    const float* Wv = (const float*)d_in[7];
    const float* bv = (const float*)d_in[8];
    const float* Wo = (const float*)d_in[9];
    const float* bo = (const float*)d_in[10];
    const float* rk = (const float*)d_in[11];
    const float* rv = (const float*)d_in[12];

    char* ws = (char*)d_ws;
    auto alloc = [&](size_t bytes) { char* p = ws; ws += bytes; return p; };
    const size_t QB = (size_t)NB * SQ * EM * 2;       // 8 MB
    const size_t WB = (size_t)EM * EM * 2;            // 2 MB

    // Ptile aliases the early bf16 staging buffers (dead before flash runs).
    char* region0 = alloc(NR * 320 * 2);              // 41.9 MB
    ushort_t* Ptile = (ushort_t*)region0;             // [NR/64][5][64][64]
    ushort_t* qbf = (ushort_t*)region0;
    ushort_t* kbf = (ushort_t*)(region0 + QB);
    ushort_t* vbf = (ushort_t*)(region0 + 2 * QB);
    ushort_t* Wqb = (ushort_t*)(region0 + 3 * QB);
    ushort_t* Wkb = (ushort_t*)(region0 + 3 * QB + WB);
    ushort_t* Wvb = (ushort_t*)(region0 + 3 * QB + 2 * WB);   // ends at 30 MB < 41.9

    ushort_t* Wob  = (ushort_t*)alloc(WB);            // survives until final GEMM
    ushort_t* qhb  = (ushort_t*)alloc(QB);            // [B,H,S,D]
    ushort_t* khb  = (ushort_t*)alloc(QB);            // [B,H,S,D]
    ushort_t* vtb  = (ushort_t*)alloc(QB);            // [B,H,D,S'] kappa-permuted
    ushort_t* wbuf = (ushort_t*)alloc(QB);            // [B,S,H,D]
    ushort_t* rvT  = (ushort_t*)alloc(64 * 256 * 2);
    ushort_t* rkb  = (ushort_t*)alloc(272 * 64 * 2);
    ushort_t* qrel = (ushort_t*)alloc(NR * QSTR * 2);
    float*    w1g  = (float*)alloc(NR * DH * 4);
    float*    lacg = (float*)alloc(NR * 4);
    float*    b0g  = (float*)alloc(NR * 4);
    float*    b256g= (float*)alloc(NR * 4);

    cvt8<<<dim3(NQE / 2048, 8), 256, 0, stream>>>(
        q, k, v, Wq, Wk, Wv, Wo, rv, rk,
        qbf, kbf, vbf, Wqb, Wkb, Wvb, Wob, rvT, rkb);

    const int M = NB * SQ;
    gemm_qkv<<<dim3(EM / 64, M / 128, 3), 256, 0, stream>>>(
        qbf, kbf, vbf, Wqb, Wkb, Wvb, bq, bk, bv, qhb, khb, vtb);
    qrel_mfma<<<(int)(NR / 64), 256, 0, stream>>>(qhb, rkb, qrel);

    attn_flash<<<dim3(32, 32), 256, 0, stream>>>(qhb, khb, vtb, qrel,
                                                 Ptile, w1g, lacg, b0g, b256g);
    band_gemm<<<(int)(NR / 64), 256, 0, stream>>>(Ptile, rvT, rv, w1g, lacg,
                                                  b0g, b256g, wbuf);
    gemm_out<<<dim3(EM / 64, M / 128), 256, 0, stream>>>(
        wbuf, Wob, bo, (float*)d_out, M, EM, EM);
}